// Round 9
// baseline (447.824 us; speedup 1.0000x reference)
//
#include <hip/hip_runtime.h>
#include <hip/hip_bf16.h>

typedef unsigned short u16;
typedef unsigned int   u32;
typedef __attribute__((ext_vector_type(8))) short bf16x8;
typedef __attribute__((ext_vector_type(4))) float f32x4;

#define NB    8192
#define NBLK  256     // 1 block per CU
#define STEPS (NB / NBLK)   // 32 batches per block

__device__ __forceinline__ u32 pack2bf(float a, float b) {
    __hip_bfloat162 h = __float22bfloat162_rn(make_float2(a, b));  // v_cvt_pk_bf16_f32
    return *reinterpret_cast<u32*>(&h);
}

__device__ __forceinline__ u16 f2bf(float x) {
    u32 u = __float_as_uint(x);
    u32 r = u + 0x7FFFu + ((u >> 16) & 1u);
    return (u16)(r >> 16);
}

// Frag-linear weights for 8-way role slices (R7 technique, re-indexed):
//   w1fr: frag f = p*8 + mt*4 + ks   (p=0..7, mt=0..1, ks=0..3), 64 frags.
//         elem(l,j) = W1[d][c], c = 32p+16mt+(l&15), d = 32ks+8*(l>>4)+j
//   w2fr: frag f = q*16 + et*8 + ks  (q=0..7, et=0..1, ks=0..7), 128 frags.
//         elem(l,j) = W2[cc][e], e = 32q+16et+(l&15), cc = 32ks+8*(l>>4)+j
__global__ __launch_bounds__(256) void prep_weights(
    const float* __restrict__ W1, const float* __restrict__ W2,
    u16* __restrict__ w1fr, u16* __restrict__ w2fr)
{
    int tid = blockIdx.x * 256 + threadIdx.x;
    if (tid < 32768) {
        const int f = tid >> 9, r = tid & 511, l = r >> 3, j = r & 7;
        const int p = f >> 3, mt = (f >> 2) & 1, ks = f & 3;
        const int c = 32 * p + 16 * mt + (l & 15);
        const int d = 32 * ks + 8 * (l >> 4) + j;
        w1fr[tid] = f2bf(W1[d * 256 + c]);
    } else {
        const int t2 = tid - 32768;
        if (t2 < 65536) {
            const int f = t2 >> 9, r = t2 & 511, l = r >> 3, j = r & 7;
            const int q = f >> 4, et = (f >> 3) & 1, ks = f & 7;
            const int e = 32 * q + 16 * et + (l & 15);
            const int cc = 32 * ks + 8 * (l >> 4) + j;
            w2fr[t2] = f2bf(W2[cc * 256 + e]);
        }
    }
}

// Producer/consumer persistent kernel. 1024 threads = 16 waves; even waves
// produce (stage X + L1 + ep1 -> h1s), odd waves consume (L2 + L3 -> out) the
// previous step's h1s. One __syncthreads per step orders ALL cross-step
// hazards (h1s W->R and R->W, xt W->R / R->W, partl W->R — each ping-pongs).
// LDS (dynamic, 100KB): xt[2] 2x16KB | h1s[2] 2x32KB | partl[2][8][64] 4KB.
__global__ __launch_bounds__(1024, 4) void pc_mlp(
    const float* __restrict__ X,
    const float* __restrict__ b1, const float* __restrict__ b2,
    const float* __restrict__ W3, const float* __restrict__ b3,
    const u16* __restrict__ w1fr, const u16* __restrict__ w2fr,
    float* __restrict__ out)
{
    extern __shared__ __align__(16) u16 smem[];
    // carves (u16 units): xt buf k at k*8192; h1s buf k at 16384 + k*16384; partl at 49152
    u16*   const xt0   = smem;
    u16*   const h10   = smem + 16384;
    float* const partl = (float*)(smem + 49152);   // [2][8][64]

    const int tid = threadIdx.x;
    const int wv  = tid >> 6;          // 0..15
    const int l   = tid & 63;
    const int lc  = l & 15;
    const int lk  = l >> 4;
    const bool isProd = (wv & 1) == 0; // even waves produce -> every SIMD gets both roles
    const int rid = wv >> 1;           // role-local id 0..7
    const int bk  = blockIdx.x;

    // ---- role-specific loop invariants ----
    // producer: bias for its c-slice, frag base
    float4 b1q[2];
    const u16* w1b = w1fr + rid * 4096 + l * 8;
    // consumer: bias/W3 for its e-slice, frag base
    float b2v[2], w3v[2];
    const u16* w2b = w2fr + rid * 8192 + l * 8;
    float b3v = 0.f;
    if (isProd) {
        #pragma unroll
        for (int mt = 0; mt < 2; ++mt)
            b1q[mt] = *(const float4*)(b1 + 32 * rid + 16 * mt + 4 * lk);
    } else {
        #pragma unroll
        for (int et = 0; et < 2; ++et) {
            const int e = 32 * rid + 16 * et + lc;
            b2v[et] = b2[e];
            w3v[et] = W3[e];
        }
        b3v = b3[0];
    }

    // ---- prologue: producers stage xt[0] for batch bk ----
    if (isProd) {
        const float* Xb = X + (size_t)bk * 8192;
        #pragma unroll
        for (int c2 = 0; c2 < 2; ++c2) {
            const int dc = rid + 8 * c2, d0 = dc << 3;
            float v[8];
            #pragma unroll
            for (int j = 0; j < 8; ++j) v[j] = Xb[(d0 + j) * 64 + l];
            u32 pk[4];
            #pragma unroll
            for (int j = 0; j < 4; ++j) pk[j] = pack2bf(v[2 * j], v[2 * j + 1]);
            *(uint4*)(xt0 + l * 128 + ((dc ^ lc) << 3)) = make_uint4(pk[0], pk[1], pk[2], pk[3]);
        }
    }
    __syncthreads();

    #pragma unroll 1
    for (int it = 0; it < STEPS + 2; ++it) {
        if (isProd) {
            if (it < STEPS) {
                const int b = bk + it * NBLK;
                // 0) issue next-batch X loads early (latency hides under L1)
                float v[2][8];
                if (it < STEPS - 1) {
                    const float* Xn = X + (size_t)(b + NBLK) * 8192;
                    #pragma unroll
                    for (int c2 = 0; c2 < 2; ++c2) {
                        const int d0 = (rid + 8 * c2) << 3;
                        #pragma unroll
                        for (int j = 0; j < 8; ++j) v[c2][j] = Xn[(d0 + j) * 64 + l];
                    }
                }
                // 1) L1 on xt[it&1]: D1[c][n] = sum_d W1[d][c]*X[d][n], bias in init
                const u16* xb = xt0 + (it & 1) * 8192;
                f32x4 acc[2][4];
                #pragma unroll
                for (int mt = 0; mt < 2; ++mt)
                    #pragma unroll
                    for (int nt = 0; nt < 4; ++nt)
                        acc[mt][nt] = (f32x4){b1q[mt].x, b1q[mt].y, b1q[mt].z, b1q[mt].w};
                bf16x8 afrN[2];
                #pragma unroll
                for (int mt = 0; mt < 2; ++mt)
                    afrN[mt] = *(const bf16x8*)(w1b + mt * 2048);
                #pragma unroll
                for (int ks = 0; ks < 4; ++ks) {
                    bf16x8 afr[2], bfr[4];
                    #pragma unroll
                    for (int mt = 0; mt < 2; ++mt) afr[mt] = afrN[mt];
                    if (ks < 3) {
                        #pragma unroll
                        for (int mt = 0; mt < 2; ++mt)
                            afrN[mt] = *(const bf16x8*)(w1b + (mt * 4 + ks + 1) * 512);
                    }
                    #pragma unroll
                    for (int nt = 0; nt < 4; ++nt)
                        bfr[nt] = *(const bf16x8*)(xb + (16 * nt + lc) * 128 + (((4 * ks + lk) ^ lc) << 3));
                    __builtin_amdgcn_s_setprio(1);
                    #pragma unroll
                    for (int mt = 0; mt < 2; ++mt)
                        #pragma unroll
                        for (int nt = 0; nt < 4; ++nt)
                            acc[mt][nt] = __builtin_amdgcn_mfma_f32_16x16x32_bf16(afr[mt], bfr[nt], acc[mt][nt], 0, 0, 0);
                    __builtin_amdgcn_s_setprio(0);
                }
                // 2) ep1: relu + pack -> h1s[it&1]
                u16* hw = h10 + (it & 1) * 16384;
                #pragma unroll
                for (int mt = 0; mt < 2; ++mt) {
                    const int c0 = 32 * rid + 16 * mt + 4 * lk;
                    #pragma unroll
                    for (int nt = 0; nt < 4; ++nt) {
                        const int n = 16 * nt + lc;
                        float x0 = fmaxf(acc[mt][nt][0], 0.f);
                        float x1 = fmaxf(acc[mt][nt][1], 0.f);
                        float x2 = fmaxf(acc[mt][nt][2], 0.f);
                        float x3 = fmaxf(acc[mt][nt][3], 0.f);
                        const int chunk = (c0 >> 3) ^ lc;
                        *(uint2*)(hw + n * 256 + (chunk << 3) + (c0 & 7)) =
                            make_uint2(pack2bf(x0, x1), pack2bf(x2, x3));
                    }
                }
                // 3) cvt staged X -> xt[(it+1)&1]
                if (it < STEPS - 1) {
                    u16* xn = xt0 + ((it + 1) & 1) * 8192;
                    #pragma unroll
                    for (int c2 = 0; c2 < 2; ++c2) {
                        const int dc = rid + 8 * c2;
                        u32 pk[4];
                        #pragma unroll
                        for (int j = 0; j < 4; ++j) pk[j] = pack2bf(v[c2][2 * j], v[c2][2 * j + 1]);
                        *(uint4*)(xn + l * 128 + ((dc ^ lc) << 3)) = make_uint4(pk[0], pk[1], pk[2], pk[3]);
                    }
                }
            }
        } else {
            // out-write for batch it-2 (partl written at step it-1)
            if (it >= 2 && it <= STEPS + 1 && wv == 1) {
                const int bo = bk + (it - 2) * NBLK;
                const float* pr = partl + ((it - 1) & 1) * 512;
                float s = b3v;
                #pragma unroll
                for (int k = 0; k < 8; ++k) s += pr[k * 64 + l];
                out[(size_t)bo * 65 + 1 + l] = s;
                if (l == 0) out[(size_t)bo * 65] = 0.f;
            }
            // L2+L3 for batch it-1 on h1s[(it-1)&1]
            if (it >= 1 && it <= STEPS) {
                const u16* hb = h10 + ((it - 1) & 1) * 16384;
                f32x4 acc2[4][2];
                #pragma unroll
                for (int mt = 0; mt < 4; ++mt)
                    #pragma unroll
                    for (int et = 0; et < 2; ++et)
                        acc2[mt][et] = (f32x4){b2v[et], b2v[et], b2v[et], b2v[et]};
                bf16x8 bfrN[2];
                #pragma unroll
                for (int et = 0; et < 2; ++et)
                    bfrN[et] = *(const bf16x8*)(w2b + et * 4096);
                #pragma unroll
                for (int ks = 0; ks < 8; ++ks) {
                    bf16x8 afr[4], bfr[2];
                    #pragma unroll
                    for (int et = 0; et < 2; ++et) bfr[et] = bfrN[et];
                    if (ks < 7) {
                        #pragma unroll
                        for (int et = 0; et < 2; ++et)
                            bfrN[et] = *(const bf16x8*)(w2b + (et * 8 + ks + 1) * 512);
                    }
                    #pragma unroll
                    for (int mt = 0; mt < 4; ++mt)
                        afr[mt] = *(const bf16x8*)(hb + (16 * mt + lc) * 256 + (((4 * ks + lk) ^ lc) << 3));
                    __builtin_amdgcn_s_setprio(1);
                    #pragma unroll
                    for (int mt = 0; mt < 4; ++mt)
                        #pragma unroll
                        for (int et = 0; et < 2; ++et)
                            acc2[mt][et] = __builtin_amdgcn_mfma_f32_16x16x32_bf16(afr[mt], bfr[et], acc2[mt][et], 0, 0, 0);
                    __builtin_amdgcn_s_setprio(0);
                }
                // L3: relu, dot W3 over e-slice, shfl-reduce 16 lanes -> partl[it&1]
                float* pw = partl + (it & 1) * 512 + rid * 64;
                #pragma unroll
                for (int mt = 0; mt < 4; ++mt) {
                    #pragma unroll
                    for (int j = 0; j < 4; ++j) {      // row n = 16mt + 4lk + j
                        float s = fmaxf(acc2[mt][0][j], 0.f) * w3v[0]
                                + fmaxf(acc2[mt][1][j], 0.f) * w3v[1];
                        s += __shfl_xor(s, 1);
                        s += __shfl_xor(s, 2);
                        s += __shfl_xor(s, 4);
                        s += __shfl_xor(s, 8);
                        if (lc == 0) pw[16 * mt + 4 * lk + j] = s;
                    }
                }
            }
        }
        __syncthreads();   // the single step barrier: orders h1s, xt, partl ping-pongs
    }
}

extern "C" void kernel_launch(void* const* d_in, const int* in_sizes, int n_in,
                              void* d_out, int out_size, void* d_ws, size_t ws_size,
                              hipStream_t stream) {
    const float* X  = (const float*)d_in[0];
    const float* W1 = (const float*)d_in[1];
    const float* b1 = (const float*)d_in[2];
    const float* W2 = (const float*)d_in[3];
    const float* b2 = (const float*)d_in[4];
    const float* W3 = (const float*)d_in[5];
    const float* b3 = (const float*)d_in[6];
    float* out = (float*)d_out;

    u16* w1fr = (u16*)d_ws;            // 64 KB
    u16* w2fr = w1fr + 32768;          // 128 KB

    prep_weights<<<384, 256, 0, stream>>>(W1, W2, w1fr, w2fr);
    pc_mlp<<<NBLK, 1024, 102400, stream>>>(X, b1, b2, W3, b3, w1fr, w2fr, out);
}

// Round 10
// 170.257 us; speedup vs baseline: 2.6303x; 2.6303x over previous
//
#include <hip/hip_runtime.h>
#include <hip/hip_bf16.h>

typedef unsigned short u16;
typedef unsigned int   u32;
typedef __attribute__((ext_vector_type(8))) short bf16x8;
typedef __attribute__((ext_vector_type(4))) float f32x4;

#define NB 8192

__device__ __forceinline__ u32 pack2bf(float a, float b) {
    __hip_bfloat162 h = __float22bfloat162_rn(make_float2(a, b));  // v_cvt_pk_bf16_f32
    return *reinterpret_cast<u32*>(&h);
}

__device__ __forceinline__ u16 f2bf(float x) {
    u32 u = __float_as_uint(x);
    u32 r = u + 0x7FFFu + ((u >> 16) & 1u);
    return (u16)(r >> 16);
}

// Fragment-linear weight layouts (R7, proven): frag f = 512 elems in lane*8 order.
//   w1fr: f = (wv*4 + mt)*4 + ks    elem(l,j): W1[d][c], d=32ks+8*(l>>4)+j, c=64wv+16mt+(l&15)
//   w2fr: f = (wv*4 + et)*8 + ks    elem(l,j): W2[c][e], c=32ks+8*(l>>4)+j, e=64wv+16et+(l&15)
__global__ __launch_bounds__(256) void prep_weights(
    const float* __restrict__ W1, const float* __restrict__ W2,
    u16* __restrict__ w1fr, u16* __restrict__ w2fr)
{
    int tid = blockIdx.x * 256 + threadIdx.x;
    if (tid < 32768) {
        const int f = tid >> 9, r = tid & 511, l = r >> 3, j = r & 7;
        const int wv = f >> 4, mt = (f >> 2) & 3, ks = f & 3;
        const int c = 64 * wv + 16 * mt + (l & 15);
        const int d = 32 * ks + 8 * (l >> 4) + j;
        w1fr[tid] = f2bf(W1[d * 256 + c]);
    } else {
        const int t2 = tid - 32768;
        if (t2 < 65536) {
            const int f = t2 >> 9, r = t2 & 511, l = r >> 3, j = r & 7;
            const int wv = f >> 5, et = (f >> 3) & 3, ks = f & 7;
            const int e = 64 * wv + 16 * et + (l & 15);
            const int c = 32 * ks + 8 * (l >> 4) + j;
            w2fr[t2] = f2bf(W2[c * 256 + e]);
        }
    }
}

// One block = one batch b: 64 nodes, 4 waves, 2 barriers total.
// L1 streams X straight from global (no LDS transpose, no phase-0 burst):
// B-frag(ks,nt) lane(l,j) = X[32ks+8lk+j][16nt+lc], 8 dword loads + 4 cvt_pk.
// The block's 4 waves read the same 32KB X-slab within ~us -> HBM once, L1/L2 reuse.
// LDS: h1s 32KB + partl 1KB. ep1/L2/L3 verbatim R7.
__global__ __launch_bounds__(256, 4) void fused_mlp(
    const float* __restrict__ X,
    const float* __restrict__ b1, const float* __restrict__ b2,
    const float* __restrict__ W3, const float* __restrict__ b3,
    const u16* __restrict__ w1fr, const u16* __restrict__ w2fr,
    float* __restrict__ out)
{
    __shared__ __align__(16) u16 h1s[64 * 256];   // bf16 h1[n][c], 16B-chunk XOR swizzle
    __shared__ float partl[4][64];

    const int tid = threadIdx.x;
    const int w   = tid >> 6;
    const int l   = tid & 63;
    const int lc  = l & 15;
    const int lk  = l >> 4;
    const int b   = blockIdx.x;
    const float* Xb = X + (size_t)b * 8192;

    const u16* w1b = w1fr + w * 8192  + l * 8;
    const u16* w2b = w2fr + w * 16384 + l * 8;

    // ---------- layer 1: D1[c][n] = sum_d W1[d][c] * X[d][n], bias folded in init ----------
    f32x4 acc[4][4];
    #pragma unroll
    for (int mt = 0; mt < 4; ++mt) {
        const float4 bq = *(const float4*)(b1 + 64 * w + 16 * mt + 4 * lk);
        #pragma unroll
        for (int nt = 0; nt < 4; ++nt)
            acc[mt][nt] = (f32x4){bq.x, bq.y, bq.z, bq.w};
    }

    const float* xbase = Xb + (8 * lk) * 64 + lc;   // + ks*2048 + j*64 + nt*16

    #pragma unroll
    for (int ks = 0; ks < 4; ++ks) {
        bf16x8 afr[4];
        #pragma unroll
        for (int mt = 0; mt < 4; ++mt)
            afr[mt] = *(const bf16x8*)(w1b + (mt * 4 + ks) * 512);

        const float* xp = xbase + ks * 2048;
        #pragma unroll
        for (int pr = 0; pr < 2; ++pr) {            // nt pairs {0,1},{2,3}
            float xv[2][8];
            #pragma unroll
            for (int t = 0; t < 2; ++t) {
                const int nt = 2 * pr + t;
                #pragma unroll
                for (int j = 0; j < 8; ++j)
                    xv[t][j] = xp[j * 64 + nt * 16];   // 4x64B segments / wave-instr
            }
            bf16x8 bfr[2];
            #pragma unroll
            for (int t = 0; t < 2; ++t) {
                union { bf16x8 v; u32 d[4]; } fr;
                #pragma unroll
                for (int j = 0; j < 4; ++j) fr.d[j] = pack2bf(xv[t][2 * j], xv[t][2 * j + 1]);
                bfr[t] = fr.v;
            }
            #pragma unroll
            for (int mt = 0; mt < 4; ++mt)
                #pragma unroll
                for (int t = 0; t < 2; ++t)
                    acc[mt][2 * pr + t] = __builtin_amdgcn_mfma_f32_16x16x32_bf16(
                        afr[mt], bfr[t], acc[mt][2 * pr + t], 0, 0, 0);
        }
    }

    // ---------- epilogue 1: relu, pack -> h1s (no prior readers; no barrier needed) ----------
    #pragma unroll
    for (int mt = 0; mt < 4; ++mt) {
        const int c0 = 64 * w + 16 * mt + 4 * lk;
        #pragma unroll
        for (int nt = 0; nt < 4; ++nt) {
            const int n = 16 * nt + lc;
            float x0 = fmaxf(acc[mt][nt][0], 0.f);
            float x1 = fmaxf(acc[mt][nt][1], 0.f);
            float x2 = fmaxf(acc[mt][nt][2], 0.f);
            float x3 = fmaxf(acc[mt][nt][3], 0.f);
            const int chunk = (c0 >> 3) ^ lc;
            *(uint2*)(h1s + n * 256 + (chunk << 3) + (c0 & 7)) =
                make_uint2(pack2bf(x0, x1), pack2bf(x2, x3));
        }
    }
    __syncthreads();                               // B1: h1s visible to all waves

    // ---------- layer 2: D2[n][e] = sum_c h1[n][c] * W2[c][e], bias folded ----------
    f32x4 acc2[4][4];
    #pragma unroll
    for (int nt = 0; nt < 4; ++nt) {
        const float bv = b2[64 * w + 16 * nt + lc];
        #pragma unroll
        for (int mt = 0; mt < 4; ++mt)
            acc2[mt][nt] = (f32x4){bv, bv, bv, bv};
    }

    bf16x8 bfrN[4];
    #pragma unroll
    for (int nt = 0; nt < 4; ++nt)
        bfrN[nt] = *(const bf16x8*)(w2b + nt * 4096);

    #pragma unroll
    for (int ks = 0; ks < 8; ++ks) {
        bf16x8 afr[4], bfr[4];
        #pragma unroll
        for (int nt = 0; nt < 4; ++nt) bfr[nt] = bfrN[nt];
        if (ks < 7) {                              // 1-deep prefetch (L2-hot weights)
            #pragma unroll
            for (int nt = 0; nt < 4; ++nt)
                bfrN[nt] = *(const bf16x8*)(w2b + (nt * 8 + ks + 1) * 512);
        }
        #pragma unroll
        for (int mt = 0; mt < 4; ++mt)
            afr[mt] = *(const bf16x8*)(h1s + (16 * mt + lc) * 256 + (((4 * ks + lk) ^ lc) << 3));
        #pragma unroll
        for (int mt = 0; mt < 4; ++mt)
            #pragma unroll
            for (int nt = 0; nt < 4; ++nt)
                acc2[mt][nt] = __builtin_amdgcn_mfma_f32_16x16x32_bf16(afr[mt], bfr[nt], acc2[mt][nt], 0, 0, 0);
    }

    // ---------- layer 3: relu, dot W3, shfl-reduce over e -> partl (separate buffer) ----------
    float w3v[4];
    #pragma unroll
    for (int nt = 0; nt < 4; ++nt)
        w3v[nt] = W3[64 * w + 16 * nt + lc];

    #pragma unroll
    for (int mt = 0; mt < 4; ++mt) {
        #pragma unroll
        for (int j = 0; j < 4; ++j) {              // row n = 16mt + 4lk + j
            float s = 0.f;
            #pragma unroll
            for (int nt = 0; nt < 4; ++nt)
                s += fmaxf(acc2[mt][nt][j], 0.f) * w3v[nt];
            s += __shfl_xor(s, 1);
            s += __shfl_xor(s, 2);
            s += __shfl_xor(s, 4);
            s += __shfl_xor(s, 8);
            if (lc == 0) partl[w][16 * mt + 4 * lk + j] = s;
        }
    }
    __syncthreads();                               // B2: partl visible

    if (tid < 64) {
        float s = partl[0][tid] + partl[1][tid] + partl[2][tid] + partl[3][tid] + b3[0];
        out[(size_t)b * 65 + 1 + tid] = s;
    } else if (tid == 64) {
        out[(size_t)b * 65] = 0.f;                 // add_zero column
    }
}

extern "C" void kernel_launch(void* const* d_in, const int* in_sizes, int n_in,
                              void* d_out, int out_size, void* d_ws, size_t ws_size,
                              hipStream_t stream) {
    const float* X  = (const float*)d_in[0];
    const float* W1 = (const float*)d_in[1];
    const float* b1 = (const float*)d_in[2];
    const float* W2 = (const float*)d_in[3];
    const float* b2 = (const float*)d_in[4];
    const float* W3 = (const float*)d_in[5];
    const float* b3 = (const float*)d_in[6];
    float* out = (float*)d_out;

    u16* w1fr = (u16*)d_ws;            // 64 KB
    u16* w2fr = w1fr + 32768;          // 128 KB

    const int B = in_sizes[0] / (128 * 64);   // 8192

    prep_weights<<<384, 256, 0, stream>>>(W1, W2, w1fr, w2fr);
    fused_mlp<<<B, 256, 0, stream>>>(X, b1, b2, W3, b3, w1fr, w2fr, out);
}

// Round 11
// 140.722 us; speedup vs baseline: 3.1823x; 1.2099x over previous
//
#include <hip/hip_runtime.h>
#include <hip/hip_bf16.h>

typedef unsigned short u16;
typedef unsigned int   u32;
typedef __attribute__((ext_vector_type(8))) short bf16x8;
typedef __attribute__((ext_vector_type(4))) float f32x4;

#define NB 8192

__device__ __forceinline__ u32 pack2bf(float a, float b) {
    __hip_bfloat162 h = __float22bfloat162_rn(make_float2(a, b));  // v_cvt_pk_bf16_f32
    return *reinterpret_cast<u32*>(&h);
}

__device__ __forceinline__ u16 f2bf(float x) {
    u32 u = __float_as_uint(x);
    u32 r = u + 0x7FFFu + ((u >> 16) & 1u);
    return (u16)(r >> 16);
}

// Frag-linear weights, 8-way wave slices (verified in R9):
//   w1fr: frag f = p*8 + mt*4 + ks   (p=0..7, mt=0..1, ks=0..3), 64 frags of 512 elems.
//         elem(l,j) = W1[d][c], c = 32p+16mt+(l&15), d = 32ks+8*(l>>4)+j
//   w2fr: frag f = q*16 + et*8 + ks  (q=0..7, et=0..1, ks=0..7), 128 frags.
//         elem(l,j) = W2[cc][e], e = 32q+16et+(l&15), cc = 32ks+8*(l>>4)+j
__global__ __launch_bounds__(256) void prep_weights(
    const float* __restrict__ W1, const float* __restrict__ W2,
    u16* __restrict__ w1fr, u16* __restrict__ w2fr)
{
    int tid = blockIdx.x * 256 + threadIdx.x;
    if (tid < 32768) {
        const int f = tid >> 9, r = tid & 511, l = r >> 3, j = r & 7;
        const int p = f >> 3, mt = (f >> 2) & 1, ks = f & 3;
        const int c = 32 * p + 16 * mt + (l & 15);
        const int d = 32 * ks + 8 * (l >> 4) + j;
        w1fr[tid] = f2bf(W1[d * 256 + c]);
    } else {
        const int t2 = tid - 32768;
        if (t2 < 65536) {
            const int f = t2 >> 9, r = t2 & 511, l = r >> 3, j = r & 7;
            const int q = f >> 4, et = (f >> 3) & 1, ks = f & 7;
            const int e = 32 * q + 16 * et + (l & 15);
            const int cc = 32 * ks + 8 * (l >> 4) + j;
            w2fr[t2] = f2bf(W2[cc * 256 + e]);
        }
    }
}

// One block = one batch, 512 threads = 8 thin waves (half-size tiles, 32-reg acc).
// 3 blocks/CU (24 waves/CU). LDS 50KB: xt 16K | h1s 32K | partl 2K (disjoint ->
// only 3 barriers). Structure/swizzles identical to R7, re-partitioned 8-way.
__global__ __launch_bounds__(512, 6) void fused_mlp(
    const float* __restrict__ X,
    const float* __restrict__ b1, const float* __restrict__ b2,
    const float* __restrict__ W3, const float* __restrict__ b3,
    const u16* __restrict__ w1fr, const u16* __restrict__ w2fr,
    float* __restrict__ out)
{
    __shared__ __align__(16) u16 xt[64 * 128];    // bf16 XT[n][d], 16B-chunk XOR swizzle
    __shared__ __align__(16) u16 h1s[64 * 256];   // bf16 h1[n][c], same swizzle family
    __shared__ float partl[8][64];

    const int tid = threadIdx.x;
    const int wv  = tid >> 6;          // 0..7
    const int l   = tid & 63;
    const int lc  = l & 15;
    const int lk  = l >> 4;
    const int b   = blockIdx.x;
    const float* Xb = X + (size_t)b * 8192;

    const u16* w1b = w1fr + wv * 4096 + l * 8;    // 8 frags (mt*4+ks)*512
    const u16* w2b = w2fr + wv * 8192 + l * 8;    // 16 frags (et*8+ks)*512

    // ---------- phase 0: X[b] (d-major) -> LDS XT[n][d] bf16; wave covers 2 d-chunks ----------
    #pragma unroll
    for (int c2 = 0; c2 < 2; ++c2) {
        const int dc = wv + 8 * c2, d0 = dc << 3;
        float v[8];
        #pragma unroll
        for (int j = 0; j < 8; ++j) v[j] = Xb[(d0 + j) * 64 + l];   // 256B contiguous per j
        u32 pk[4];
        #pragma unroll
        for (int j = 0; j < 4; ++j) pk[j] = pack2bf(v[2 * j], v[2 * j + 1]);
        *(uint4*)(xt + l * 128 + ((dc ^ lc) << 3)) = make_uint4(pk[0], pk[1], pk[2], pk[3]);
    }

    // hoist ks=0 A-frags above the barrier (no LDS dep)
    bf16x8 afrN[2];
    #pragma unroll
    for (int mt = 0; mt < 2; ++mt)
        afrN[mt] = *(const bf16x8*)(w1b + mt * 2048);
    __syncthreads();                               // B0: xt valid

    // ---------- layer 1: D1[c][n] = sum_d W1[d][c]*X[d][n], c-slice 32/wave, bias in init ----------
    f32x4 acc[2][4];
    #pragma unroll
    for (int mt = 0; mt < 2; ++mt) {
        const float4 bq = *(const float4*)(b1 + 32 * wv + 16 * mt + 4 * lk);
        #pragma unroll
        for (int nt = 0; nt < 4; ++nt)
            acc[mt][nt] = (f32x4){bq.x, bq.y, bq.z, bq.w};
    }

    #pragma unroll
    for (int ks = 0; ks < 4; ++ks) {
        bf16x8 afr[2], bfr[4];
        #pragma unroll
        for (int mt = 0; mt < 2; ++mt) afr[mt] = afrN[mt];
        if (ks < 3) {
            #pragma unroll
            for (int mt = 0; mt < 2; ++mt)
                afrN[mt] = *(const bf16x8*)(w1b + (mt * 4 + ks + 1) * 512);
        }
        #pragma unroll
        for (int nt = 0; nt < 4; ++nt)
            bfr[nt] = *(const bf16x8*)(xt + (16 * nt + lc) * 128 + (((4 * ks + lk) ^ lc) << 3));
        #pragma unroll
        for (int mt = 0; mt < 2; ++mt)
            #pragma unroll
            for (int nt = 0; nt < 4; ++nt)
                acc[mt][nt] = __builtin_amdgcn_mfma_f32_16x16x32_bf16(afr[mt], bfr[nt], acc[mt][nt], 0, 0, 0);
    }

    // ---------- epilogue 1: relu, pack -> h1s (disjoint from xt: no barrier needed) ----------
    #pragma unroll
    for (int mt = 0; mt < 2; ++mt) {
        const int c0 = 32 * wv + 16 * mt + 4 * lk;
        #pragma unroll
        for (int nt = 0; nt < 4; ++nt) {
            const int n = 16 * nt + lc;
            float x0 = fmaxf(acc[mt][nt][0], 0.f);
            float x1 = fmaxf(acc[mt][nt][1], 0.f);
            float x2 = fmaxf(acc[mt][nt][2], 0.f);
            float x3 = fmaxf(acc[mt][nt][3], 0.f);
            const int chunk = (c0 >> 3) ^ lc;      // 5-bit chunk, XOR low 4
            *(uint2*)(h1s + n * 256 + (chunk << 3) + (c0 & 7)) =
                make_uint2(pack2bf(x0, x1), pack2bf(x2, x3));
        }
    }

    // hoist ks=0 B-frags above the barrier
    bf16x8 bfrN[2];
    #pragma unroll
    for (int et = 0; et < 2; ++et)
        bfrN[et] = *(const bf16x8*)(w2b + et * 4096);
    __syncthreads();                               // B1: h1s visible

    // ---------- layer 2: D2[n][e] = sum_c h1[n][c]*W2[c][e], e-slice 32/wave, bias in init ----------
    f32x4 acc2[4][2];
    float w3v[2];
    #pragma unroll
    for (int et = 0; et < 2; ++et) {
        const int e = 32 * wv + 16 * et + lc;
        const float bv = b2[e];
        w3v[et] = W3[e];
        #pragma unroll
        for (int mt = 0; mt < 4; ++mt)
            acc2[mt][et] = (f32x4){bv, bv, bv, bv};
    }

    #pragma unroll
    for (int ks = 0; ks < 8; ++ks) {
        bf16x8 afr[4], bfr[2];
        #pragma unroll
        for (int et = 0; et < 2; ++et) bfr[et] = bfrN[et];
        if (ks < 7) {
            #pragma unroll
            for (int et = 0; et < 2; ++et)
                bfrN[et] = *(const bf16x8*)(w2b + (et * 8 + ks + 1) * 512);
        }
        #pragma unroll
        for (int mt = 0; mt < 4; ++mt)
            afr[mt] = *(const bf16x8*)(h1s + (16 * mt + lc) * 256 + (((4 * ks + lk) ^ lc) << 3));
        #pragma unroll
        for (int mt = 0; mt < 4; ++mt)
            #pragma unroll
            for (int et = 0; et < 2; ++et)
                acc2[mt][et] = __builtin_amdgcn_mfma_f32_16x16x32_bf16(afr[mt], bfr[et], acc2[mt][et], 0, 0, 0);
    }

    // ---------- layer 3: relu, dot W3 over e-slice, shfl-reduce 16 lanes -> partl ----------
    #pragma unroll
    for (int mt = 0; mt < 4; ++mt) {
        #pragma unroll
        for (int j = 0; j < 4; ++j) {              // row n = 16mt + 4lk + j
            float s = fmaxf(acc2[mt][0][j], 0.f) * w3v[0]
                    + fmaxf(acc2[mt][1][j], 0.f) * w3v[1];
            s += __shfl_xor(s, 1);
            s += __shfl_xor(s, 2);
            s += __shfl_xor(s, 4);
            s += __shfl_xor(s, 8);                 // sum over 16 e-lanes
            if (lc == 0) partl[wv][16 * mt + 4 * lk + j] = s;
        }
    }
    __syncthreads();                               // B2: partl visible

    if (tid < 64) {
        float s = b3[0];
        #pragma unroll
        for (int k = 0; k < 8; ++k) s += partl[k][tid];
        out[(size_t)b * 65 + 1 + tid] = s;
    } else if (tid == 64) {
        out[(size_t)b * 65] = 0.f;                 // add_zero column
    }
}

extern "C" void kernel_launch(void* const* d_in, const int* in_sizes, int n_in,
                              void* d_out, int out_size, void* d_ws, size_t ws_size,
                              hipStream_t stream) {
    const float* X  = (const float*)d_in[0];
    const float* W1 = (const float*)d_in[1];
    const float* b1 = (const float*)d_in[2];
    const float* W2 = (const float*)d_in[3];
    const float* b2 = (const float*)d_in[4];
    const float* W3 = (const float*)d_in[5];
    const float* b3 = (const float*)d_in[6];
    float* out = (float*)d_out;

    u16* w1fr = (u16*)d_ws;            // 64 KB
    u16* w2fr = w1fr + 32768;          // 128 KB

    const int B = in_sizes[0] / (128 * 64);   // 8192

    prep_weights<<<384, 256, 0, stream>>>(W1, W2, w1fr, w2fr);
    fused_mlp<<<B, 512, 0, stream>>>(X, b1, b2, W3, b3, w1fr, w2fr, out);
}

// Round 12
// 138.066 us; speedup vs baseline: 3.2436x; 1.0192x over previous
//
#include <hip/hip_runtime.h>
#include <hip/hip_bf16.h>

typedef unsigned short u16;
typedef unsigned int   u32;
typedef __attribute__((ext_vector_type(8))) short bf16x8;
typedef __attribute__((ext_vector_type(4))) float f32x4;

#define NB 8192

__device__ __forceinline__ u32 pack2bf(float a, float b) {
    __hip_bfloat162 h = __float22bfloat162_rn(make_float2(a, b));  // v_cvt_pk_bf16_f32
    return *reinterpret_cast<u32*>(&h);
}

__device__ __forceinline__ u16 f2bf(float x) {
    u32 u = __float_as_uint(x);
    u32 r = u + 0x7FFFu + ((u >> 16) & 1u);
    return (u16)(r >> 16);
}

// Frag-linear weights, 8-way wave slices (verified R9/R11):
//   w1fr: frag f = p*8 + mt*4 + ks   (p=0..7, mt=0..1, ks=0..3), 64 frags of 512 elems.
//         elem(l,j) = W1[d][c], c = 32p+16mt+(l&15), d = 32ks+8*(l>>4)+j
//   w2fr: frag f = q*16 + et*8 + ks  (q=0..7, et=0..1, ks=0..7), 128 frags.
//         elem(l,j) = W2[cc][e], e = 32q+16et+(l&15), cc = 32ks+8*(l>>4)+j
__global__ __launch_bounds__(256) void prep_weights(
    const float* __restrict__ W1, const float* __restrict__ W2,
    u16* __restrict__ w1fr, u16* __restrict__ w2fr)
{
    int tid = blockIdx.x * 256 + threadIdx.x;
    if (tid < 32768) {
        const int f = tid >> 9, r = tid & 511, l = r >> 3, j = r & 7;
        const int p = f >> 3, mt = (f >> 2) & 1, ks = f & 3;
        const int c = 32 * p + 16 * mt + (l & 15);
        const int d = 32 * ks + 8 * (l >> 4) + j;
        w1fr[tid] = f2bf(W1[d * 256 + c]);
    } else {
        const int t2 = tid - 32768;
        if (t2 < 65536) {
            const int f = t2 >> 9, r = t2 & 511, l = r >> 3, j = r & 7;
            const int q = f >> 4, et = (f >> 3) & 1, ks = f & 7;
            const int e = 32 * q + 16 * et + (l & 15);
            const int cc = 32 * ks + 8 * (l >> 4) + j;
            w2fr[t2] = f2bf(W2[cc * 256 + e]);
        }
    }
}

// One block = TWO batches (2*bid, 2*bid+1): weights loaded once per ks, used
// for both -> per-batch weight traffic and barrier count halved vs R7/R11.
// 512 threads = 8 thin waves. LDS: 64KB arena (xt[2] 32KB -> h1s[2] 64KB,
// aliased, disjoint lifetimes) + 4KB partl => 2 blocks/CU (16 waves/CU,
// the R7 regime). 4 barriers per block (= 2 per batch).
__global__ __launch_bounds__(512, 4) void fused_mlp(
    const float* __restrict__ X,
    const float* __restrict__ b1, const float* __restrict__ b2,
    const float* __restrict__ W3, const float* __restrict__ b3,
    const u16* __restrict__ w1fr, const u16* __restrict__ w2fr,
    float* __restrict__ out)
{
    __shared__ __align__(16) u16 arena[2 * 64 * 256];   // 64 KB
    __shared__ float partl[2][8][64];                   // 4 KB

    const int tid = threadIdx.x;
    const int wv  = tid >> 6;          // 0..7
    const int l   = tid & 63;
    const int lc  = l & 15;
    const int lk  = l >> 4;
    const int b0  = 2 * blockIdx.x;

    const u16* w1b = w1fr + wv * 4096 + l * 8;    // 8 frags (mt*4+ks)*512
    const u16* w2b = w2fr + wv * 8192 + l * 8;    // 16 frags (et*8+ks)*512

    // ---------- phase 0: stage X for both batches -> xt[bb] (bb*8192 in arena) ----------
    #pragma unroll
    for (int bb = 0; bb < 2; ++bb) {
        const float* Xb = X + (size_t)(b0 + bb) * 8192;
        u16* xt = arena + bb * 8192;
        #pragma unroll
        for (int c2 = 0; c2 < 2; ++c2) {
            const int dc = wv + 8 * c2, d0 = dc << 3;
            float v[8];
            #pragma unroll
            for (int j = 0; j < 8; ++j) v[j] = Xb[(d0 + j) * 64 + l];   // 256B/instr coalesced
            u32 pk[4];
            #pragma unroll
            for (int j = 0; j < 4; ++j) pk[j] = pack2bf(v[2 * j], v[2 * j + 1]);
            *(uint4*)(xt + l * 128 + ((dc ^ lc) << 3)) = make_uint4(pk[0], pk[1], pk[2], pk[3]);
        }
    }

    // hoist ks=0 A-frags (no LDS dep)
    bf16x8 afrN[2];
    #pragma unroll
    for (int mt = 0; mt < 2; ++mt)
        afrN[mt] = *(const bf16x8*)(w1b + mt * 2048);
    __syncthreads();                               // B0: xt valid

    // ---------- layer 1: D1[c][n], c-slice 32/wave, both batches per weight load ----------
    f32x4 acc[2][2][4];                            // [bb][mt][nt] = 64 VGPR
    #pragma unroll
    for (int mt = 0; mt < 2; ++mt) {
        const float4 bq = *(const float4*)(b1 + 32 * wv + 16 * mt + 4 * lk);
        #pragma unroll
        for (int bb = 0; bb < 2; ++bb)
            #pragma unroll
            for (int nt = 0; nt < 4; ++nt)
                acc[bb][mt][nt] = (f32x4){bq.x, bq.y, bq.z, bq.w};
    }

    #pragma unroll
    for (int ks = 0; ks < 4; ++ks) {
        bf16x8 afr[2];
        #pragma unroll
        for (int mt = 0; mt < 2; ++mt) afr[mt] = afrN[mt];
        if (ks < 3) {
            #pragma unroll
            for (int mt = 0; mt < 2; ++mt)
                afrN[mt] = *(const bf16x8*)(w1b + (mt * 4 + ks + 1) * 512);
        }
        #pragma unroll
        for (int bb = 0; bb < 2; ++bb) {
            const u16* xt = arena + bb * 8192;
            bf16x8 bfr[4];
            #pragma unroll
            for (int nt = 0; nt < 4; ++nt)
                bfr[nt] = *(const bf16x8*)(xt + (16 * nt + lc) * 128 + (((4 * ks + lk) ^ lc) << 3));
            #pragma unroll
            for (int mt = 0; mt < 2; ++mt)
                #pragma unroll
                for (int nt = 0; nt < 4; ++nt)
                    acc[bb][mt][nt] = __builtin_amdgcn_mfma_f32_16x16x32_bf16(afr[mt], bfr[nt], acc[bb][mt][nt], 0, 0, 0);
        }
    }
    __syncthreads();                               // B1: all xt reads done (arena reuse below)

    // ---------- epilogue 1: relu, pack -> h1s[bb] (bb*16384 in arena, overwrites xt) ----------
    #pragma unroll
    for (int bb = 0; bb < 2; ++bb) {
        u16* h1s = arena + bb * 16384;
        #pragma unroll
        for (int mt = 0; mt < 2; ++mt) {
            const int c0 = 32 * wv + 16 * mt + 4 * lk;
            #pragma unroll
            for (int nt = 0; nt < 4; ++nt) {
                const int n = 16 * nt + lc;
                float x0 = fmaxf(acc[bb][mt][nt][0], 0.f);
                float x1 = fmaxf(acc[bb][mt][nt][1], 0.f);
                float x2 = fmaxf(acc[bb][mt][nt][2], 0.f);
                float x3 = fmaxf(acc[bb][mt][nt][3], 0.f);
                const int chunk = (c0 >> 3) ^ lc;
                *(uint2*)(h1s + n * 256 + (chunk << 3) + (c0 & 7)) =
                    make_uint2(pack2bf(x0, x1), pack2bf(x2, x3));
            }
        }
    }

    // hoist ks=0 B-frags
    bf16x8 bfrN[2];
    #pragma unroll
    for (int et = 0; et < 2; ++et)
        bfrN[et] = *(const bf16x8*)(w2b + et * 4096);
    __syncthreads();                               // B2: h1s visible

    // ---------- layer 2: D2[n][e], e-slice 32/wave, both batches per weight load ----------
    f32x4 acc2[2][4][2];                           // [bb][mt][et] = 64 VGPR
    float w3v[2];
    #pragma unroll
    for (int et = 0; et < 2; ++et) {
        const int e = 32 * wv + 16 * et + lc;
        const float bv = b2[e];
        w3v[et] = W3[e];
        #pragma unroll
        for (int bb = 0; bb < 2; ++bb)
            #pragma unroll
            for (int mt = 0; mt < 4; ++mt)
                acc2[bb][mt][et] = (f32x4){bv, bv, bv, bv};
    }

    #pragma unroll
    for (int ks = 0; ks < 8; ++ks) {
        bf16x8 bfrW[2];
        #pragma unroll
        for (int et = 0; et < 2; ++et) bfrW[et] = bfrN[et];
        if (ks < 7) {
            #pragma unroll
            for (int et = 0; et < 2; ++et)
                bfrN[et] = *(const bf16x8*)(w2b + (et * 8 + ks + 1) * 512);
        }
        #pragma unroll
        for (int bb = 0; bb < 2; ++bb) {
            const u16* h1s = arena + bb * 16384;
            bf16x8 afr[4];
            #pragma unroll
            for (int mt = 0; mt < 4; ++mt)
                afr[mt] = *(const bf16x8*)(h1s + (16 * mt + lc) * 256 + (((4 * ks + lk) ^ lc) << 3));
            #pragma unroll
            for (int mt = 0; mt < 4; ++mt)
                #pragma unroll
                for (int et = 0; et < 2; ++et)
                    acc2[bb][mt][et] = __builtin_amdgcn_mfma_f32_16x16x32_bf16(afr[mt], bfrW[et], acc2[bb][mt][et], 0, 0, 0);
        }
    }

    // ---------- layer 3: relu, dot W3 over e-slice, shfl-reduce -> partl[bb] ----------
    #pragma unroll
    for (int bb = 0; bb < 2; ++bb) {
        #pragma unroll
        for (int mt = 0; mt < 4; ++mt) {
            #pragma unroll
            for (int j = 0; j < 4; ++j) {          // row n = 16mt + 4lk + j
                float s = fmaxf(acc2[bb][mt][0][j], 0.f) * w3v[0]
                        + fmaxf(acc2[bb][mt][1][j], 0.f) * w3v[1];
                s += __shfl_xor(s, 1);
                s += __shfl_xor(s, 2);
                s += __shfl_xor(s, 4);
                s += __shfl_xor(s, 8);             // sum over 16 e-lanes
                if (lc == 0) partl[bb][wv][16 * mt + 4 * lk + j] = s;
            }
        }
    }
    __syncthreads();                               // B3: partl visible

    if (tid < 128) {
        const int bb = tid >> 6, n = tid & 63;
        float s = b3[0];
        #pragma unroll
        for (int k = 0; k < 8; ++k) s += partl[bb][k][n];
        out[(size_t)(b0 + bb) * 65 + 1 + n] = s;
    } else if (tid == 128) {
        out[(size_t)b0 * 65] = 0.f;
    } else if (tid == 129) {
        out[(size_t)(b0 + 1) * 65] = 0.f;
    }
}

extern "C" void kernel_launch(void* const* d_in, const int* in_sizes, int n_in,
                              void* d_out, int out_size, void* d_ws, size_t ws_size,
                              hipStream_t stream) {
    const float* X  = (const float*)d_in[0];
    const float* W1 = (const float*)d_in[1];
    const float* b1 = (const float*)d_in[2];
    const float* W2 = (const float*)d_in[3];
    const float* b2 = (const float*)d_in[4];
    const float* W3 = (const float*)d_in[5];
    const float* b3 = (const float*)d_in[6];
    float* out = (float*)d_out;

    u16* w1fr = (u16*)d_ws;            // 64 KB
    u16* w2fr = w1fr + 32768;          // 128 KB

    const int B = in_sizes[0] / (128 * 64);   // 8192

    prep_weights<<<384, 256, 0, stream>>>(W1, W2, w1fr, w2fr);
    fused_mlp<<<B / 2, 512, 0, stream>>>(X, b1, b2, W3, b3, w1fr, w2fr, out);
}

// Round 13
// 137.016 us; speedup vs baseline: 3.2684x; 1.0077x over previous
//
#include <hip/hip_runtime.h>
#include <hip/hip_bf16.h>

typedef unsigned short u16;
typedef unsigned int   u32;
typedef __attribute__((ext_vector_type(8))) short bf16x8;
typedef __attribute__((ext_vector_type(4))) float f32x4;

#define NB 8192

__device__ __forceinline__ u32 pack2bf(float a, float b) {
    __hip_bfloat162 h = __float22bfloat162_rn(make_float2(a, b));  // v_cvt_pk_bf16_f32
    return *reinterpret_cast<u32*>(&h);
}

__device__ __forceinline__ u16 f2bf(float x) {
    u32 u = __float_as_uint(x);
    u32 r = u + 0x7FFFu + ((u >> 16) & 1u);
    return (u16)(r >> 16);
}

// Fragment-linear weight layouts (R7, proven): frag f = 512 elems in lane*8 order.
//   w1fr: f = (wv*4 + mt)*4 + ks    elem(l,j): W1[d][c], d=32ks+8*(l>>4)+j, c=64wv+16mt+(l&15)
//   w2fr: f = (wv*4 + et)*8 + ks    elem(l,j): W2[c][e], c=32ks+8*(l>>4)+j, e=64wv+16et+(l&15)
__global__ __launch_bounds__(256) void prep_weights(
    const float* __restrict__ W1, const float* __restrict__ W2,
    u16* __restrict__ w1fr, u16* __restrict__ w2fr)
{
    int tid = blockIdx.x * 256 + threadIdx.x;
    if (tid < 32768) {
        const int f = tid >> 9, r = tid & 511, l = r >> 3, j = r & 7;
        const int wv = f >> 4, mt = (f >> 2) & 3, ks = f & 3;
        const int c = 64 * wv + 16 * mt + (l & 15);
        const int d = 32 * ks + 8 * (l >> 4) + j;
        w1fr[tid] = f2bf(W1[d * 256 + c]);
    } else {
        const int t2 = tid - 32768;
        if (t2 < 65536) {
            const int f = t2 >> 9, r = t2 & 511, l = r >> 3, j = r & 7;
            const int wv = f >> 5, et = (f >> 3) & 3, ks = f & 7;
            const int e = 64 * wv + 16 * et + (l & 15);
            const int c = 32 * ks + 8 * (l >> 4) + j;
            w2fr[t2] = f2bf(W2[c * 256 + e]);
        }
    }
}

// R7 champion + bias-fold + separate partl (4 barriers instead of 5).
// One block = one batch b: 64 nodes, 4 waves. 32KB arena (xt 16K -> h1s 32K,
// aliased, disjoint lifetimes) + 1KB partl => 33.75KB, 4 blocks/CU.
// Weight frag loads: contiguous 1KB per wave-instruction (frag-linear layout).
__global__ __launch_bounds__(256, 4) void fused_mlp(
    const float* __restrict__ X,
    const float* __restrict__ b1, const float* __restrict__ b2,
    const float* __restrict__ W3, const float* __restrict__ b3,
    const u16* __restrict__ w1fr, const u16* __restrict__ w2fr,
    float* __restrict__ out)
{
    __shared__ __align__(16) u16 smem[64 * 256];  // 32 KB arena
    u16* xt   = smem;                 // bf16 XT[n][d], 16B-chunk XOR-swizzled by (n&15)
    u16* h1s  = smem;                 // bf16 h1[n][c], same swizzle; overwrites xt
    __shared__ float partl[4][64];    // separate: kills the h1s/partl WAR barrier

    const int tid = threadIdx.x;
    const int w   = tid >> 6;
    const int l   = tid & 63;
    const int lc  = l & 15;
    const int lk  = l >> 4;
    const int b   = blockIdx.x;
    const float* Xb = X + (size_t)b * 8192;

    const u16* w1b = w1fr + w * 8192  + l * 8;   // per-wave frag base (elems)
    const u16* w2b = w2fr + w * 16384 + l * 8;

    // ---------- phase 0: X[b] (d-major) -> LDS XT[n][d] bf16 ----------
    #pragma unroll
    for (int it = 0; it < 4; ++it) {
        const int dc = w + 4 * it, d0 = dc << 3;
        float v[8];
        #pragma unroll
        for (int j = 0; j < 8; ++j) v[j] = Xb[(d0 + j) * 64 + l];   // coalesced per j
        u32 pk[4];
        #pragma unroll
        for (int j = 0; j < 4; ++j) pk[j] = pack2bf(v[2 * j], v[2 * j + 1]);
        *(uint4*)(xt + l * 128 + ((dc ^ lc) << 3)) = make_uint4(pk[0], pk[1], pk[2], pk[3]);
    }

    // hoist ks=0 A-frag loads above the barrier (contiguous 1KB each)
    bf16x8 afrN[4];
    #pragma unroll
    for (int mt = 0; mt < 4; ++mt)
        afrN[mt] = *(const bf16x8*)(w1b + mt * 2048);
    __syncthreads();                               // B0: xt valid

    // ---------- layer 1: D1[c][n] = sum_d W1[d][c] * X[d][n], bias folded in init ----------
    f32x4 acc[4][4];
    #pragma unroll
    for (int mt = 0; mt < 4; ++mt) {
        const float4 bq = *(const float4*)(b1 + 64 * w + 16 * mt + 4 * lk);
        #pragma unroll
        for (int nt = 0; nt < 4; ++nt)
            acc[mt][nt] = (f32x4){bq.x, bq.y, bq.z, bq.w};
    }

    #pragma unroll
    for (int ks = 0; ks < 4; ++ks) {
        bf16x8 afr[4], bfr[4];
        #pragma unroll
        for (int mt = 0; mt < 4; ++mt) afr[mt] = afrN[mt];
        if (ks < 3) {                              // 1-deep prefetch, contiguous 1KB
            #pragma unroll
            for (int mt = 0; mt < 4; ++mt)
                afrN[mt] = *(const bf16x8*)(w1b + (mt * 4 + ks + 1) * 512);
        }
        #pragma unroll
        for (int nt = 0; nt < 4; ++nt)
            bfr[nt] = *(const bf16x8*)(xt + (16 * nt + lc) * 128 + (((4 * ks + lk) ^ lc) << 3));
        #pragma unroll
        for (int mt = 0; mt < 4; ++mt)
            #pragma unroll
            for (int nt = 0; nt < 4; ++nt)
                acc[mt][nt] = __builtin_amdgcn_mfma_f32_16x16x32_bf16(afr[mt], bfr[nt], acc[mt][nt], 0, 0, 0);
    }
    __syncthreads();                               // B1: xt readers done before h1 overwrite

    // ---------- epilogue 1: relu, pack -> h1s ----------
    #pragma unroll
    for (int mt = 0; mt < 4; ++mt) {
        const int c0 = 64 * w + 16 * mt + 4 * lk;
        #pragma unroll
        for (int nt = 0; nt < 4; ++nt) {
            const int n = 16 * nt + lc;
            float x0 = fmaxf(acc[mt][nt][0], 0.f);
            float x1 = fmaxf(acc[mt][nt][1], 0.f);
            float x2 = fmaxf(acc[mt][nt][2], 0.f);
            float x3 = fmaxf(acc[mt][nt][3], 0.f);
            const int chunk = (c0 >> 3) ^ lc;
            *(uint2*)(h1s + n * 256 + (chunk << 3) + (c0 & 7)) =
                make_uint2(pack2bf(x0, x1), pack2bf(x2, x3));
        }
    }

    // hoist ks=0 B-frag loads above the barrier
    bf16x8 bfrN[4];
    #pragma unroll
    for (int nt = 0; nt < 4; ++nt)
        bfrN[nt] = *(const bf16x8*)(w2b + nt * 4096);
    __syncthreads();                               // B2: h1s visible

    // ---------- layer 2: D2[n][e] = sum_c h1[n][c] * W2[c][e], bias folded in init ----------
    f32x4 acc2[4][4];
    float w3v[4];
    #pragma unroll
    for (int nt = 0; nt < 4; ++nt) {
        const int e = 64 * w + 16 * nt + lc;
        const float bv = b2[e];
        w3v[nt] = W3[e];
        #pragma unroll
        for (int mt = 0; mt < 4; ++mt)
            acc2[mt][nt] = (f32x4){bv, bv, bv, bv};
    }

    #pragma unroll
    for (int ks = 0; ks < 8; ++ks) {
        bf16x8 afr[4], bfr[4];
        #pragma unroll
        for (int nt = 0; nt < 4; ++nt) bfr[nt] = bfrN[nt];
        if (ks < 7) {
            #pragma unroll
            for (int nt = 0; nt < 4; ++nt)
                bfrN[nt] = *(const bf16x8*)(w2b + (nt * 8 + ks + 1) * 512);
        }
        #pragma unroll
        for (int mt = 0; mt < 4; ++mt)
            afr[mt] = *(const bf16x8*)(h1s + (16 * mt + lc) * 256 + (((4 * ks + lk) ^ lc) << 3));
        #pragma unroll
        for (int mt = 0; mt < 4; ++mt)
            #pragma unroll
            for (int nt = 0; nt < 4; ++nt)
                acc2[mt][nt] = __builtin_amdgcn_mfma_f32_16x16x32_bf16(afr[mt], bfr[nt], acc2[mt][nt], 0, 0, 0);
    }

    // ---------- layer 3: relu, dot W3, shfl-reduce over e -> partl ----------
    #pragma unroll
    for (int mt = 0; mt < 4; ++mt) {
        #pragma unroll
        for (int j = 0; j < 4; ++j) {              // row n = 16mt + 4lk + j
            float s = 0.f;
            #pragma unroll
            for (int nt = 0; nt < 4; ++nt)
                s += fmaxf(acc2[mt][nt][j], 0.f) * w3v[nt];
            s += __shfl_xor(s, 1);
            s += __shfl_xor(s, 2);
            s += __shfl_xor(s, 4);
            s += __shfl_xor(s, 8);                 // sum over 16 e-lanes
            if (lc == 0) partl[w][16 * mt + 4 * lk + j] = s;
        }
    }
    __syncthreads();                               // B3: partl visible

    if (tid < 64) {
        float s = partl[0][tid] + partl[1][tid] + partl[2][tid] + partl[3][tid] + b3[0];
        out[(size_t)b * 65 + 1 + tid] = s;
    } else if (tid == 64) {
        out[(size_t)b * 65] = 0.f;                 // add_zero column
    }
}

extern "C" void kernel_launch(void* const* d_in, const int* in_sizes, int n_in,
                              void* d_out, int out_size, void* d_ws, size_t ws_size,
                              hipStream_t stream) {
    const float* X  = (const float*)d_in[0];
    const float* W1 = (const float*)d_in[1];
    const float* b1 = (const float*)d_in[2];
    const float* W2 = (const float*)d_in[3];
    const float* b2 = (const float*)d_in[4];
    const float* W3 = (const float*)d_in[5];
    const float* b3 = (const float*)d_in[6];
    float* out = (float*)d_out;

    u16* w1fr = (u16*)d_ws;            // 64 KB
    u16* w2fr = w1fr + 32768;          // 128 KB

    const int B = in_sizes[0] / (128 * 64);   // 8192

    prep_weights<<<384, 256, 0, stream>>>(W1, W2, w1fr, w2fr);
    fused_mlp<<<B, 256, 0, stream>>>(X, b1, b2, W3, b3, w1fr, w2fr, out);
}